// Round 5
// baseline (462.518 us; speedup 1.0000x reference)
//
#include <hip/hip_runtime.h>

// ---------------- types / helpers ----------------
typedef __attribute__((ext_vector_type(8))) short short8v;    // 8 bf16 (4 VGPR)
typedef __attribute__((ext_vector_type(16))) float float16v;  // 32x32 MFMA acc
typedef unsigned short ushortT;

__device__ __forceinline__ unsigned short f2bf(float f) {
  union { float f; unsigned u; } a; a.f = f;
  unsigned r = a.u + 0x7fffu + ((a.u >> 16) & 1u);   // RNE
  return (unsigned short)(r >> 16);
}
__device__ __forceinline__ float2 up2(unsigned u) {  // packed 2xbf16 -> 2 floats
  union { unsigned u; float f; } a, b;
  a.u = u << 16; b.u = u & 0xffff0000u;
  return make_float2(a.f, b.f);
}
__device__ __forceinline__ void gl_lds16(const void* g, void* l) {
  __builtin_amdgcn_global_load_lds(
      (const __attribute__((address_space(1))) void*)g,
      (__attribute__((address_space(3))) void*)l, 16, 0, 0);
}

#define WAITV4 asm volatile("s_waitcnt vmcnt(4)" ::: "memory")
#define WAITV0 asm volatile("s_waitcnt vmcnt(0)" ::: "memory")
#define LGKM0  asm volatile("s_waitcnt lgkmcnt(0)" ::: "memory")
#define BAR()  __builtin_amdgcn_s_barrier()
#define MFMA32(d, a, b) d = __builtin_amdgcn_mfma_f32_32x32x16_bf16(a, b, d, 0, 0, 0)

// ---------------- K0: fp32 -> bf16 weight convert ----------------
__global__ __launch_bounds__(256) void wconv(const float* __restrict__ src,
                                             ushortT* __restrict__ dst, int n) {
  int i = (blockIdx.x * 256 + threadIdx.x) * 4;
  if (i < n) {
    float4 v = *(const float4*)(src + i);
    uint2 o;
    o.x = (unsigned)f2bf(v.x) | ((unsigned)f2bf(v.y) << 16);
    o.y = (unsigned)f2bf(v.z) | ((unsigned)f2bf(v.w) << 16);
    *(uint2*)(dst + i) = o;
  }
}

// ---------------- K1: groupnorm stats (one block per (b,g)) ----------------
__global__ __launch_bounds__(256) void gn_stats(const float* __restrict__ x,
                                                float2* __restrict__ stats) {
  int bg = blockIdx.x;
  const float* base = x + (size_t)bg * 65536;
  int tid = threadIdx.x;
  float s = 0.f, s2 = 0.f;
  for (int i = tid; i < 16384; i += 256) {
    float4 v = *(const float4*)(base + (size_t)i * 4);
    s  += v.x + v.y + v.z + v.w;
    s2 += v.x * v.x + v.y * v.y + v.z * v.z + v.w * v.w;
  }
  #pragma unroll
  for (int off = 32; off > 0; off >>= 1) {
    s  += __shfl_down(s, off);
    s2 += __shfl_down(s2, off);
  }
  __shared__ float red[8];
  int w = tid >> 6, l = tid & 63;
  if (l == 0) { red[w] = s; red[w + 4] = s2; }
  __syncthreads();
  if (tid == 0) {
    float ts = red[0] + red[1] + red[2] + red[3];
    float t2 = red[4] + red[5] + red[6] + red[7];
    float mean = ts * (1.f / 65536.f);
    float var  = t2 * (1.f / 65536.f) - mean * mean;
    stats[bg] = make_float2(mean, rsqrtf(var + 1e-5f));
  }
}

// ---------------- K2: normalize + transpose -> h[b*n][c] bf16 ----------------
__global__ __launch_bounds__(512) void norm_tr(const float* __restrict__ x,
                                               const float* __restrict__ nw,
                                               const float* __restrict__ nb,
                                               const float2* __restrict__ stats,
                                               ushortT* __restrict__ h) {
  __shared__ float t[64][65];
  int n0 = blockIdx.x * 64, c0 = blockIdx.y * 64, b = blockIdx.z;
  int tx = threadIdx.x, ty = threadIdx.y;
  #pragma unroll
  for (int j = ty; j < 64; j += 8) {
    int c = c0 + j;
    float2 ms = stats[b * 32 + (c >> 4)];
    float v = x[((size_t)b * 512 + c) * 4096 + n0 + tx];
    t[j][tx] = (v - ms.x) * ms.y * nw[c] + nb[c];
  }
  __syncthreads();
  #pragma unroll
  for (int j = ty; j < 64; j += 8) {
    int n = n0 + j;
    h[((size_t)b * 4096 + n) * 512 + c0 + tx] = f2bf(t[tx][j]);
  }
}

// ================= 256x256 8-wave GEMM core, 32x32x16 MFMA =================
// K=512, BK=64, 2 LDS buffers of 64KB. Same barrier/stage/vmcnt skeleton as
// the R4 8-phase port (race-free region map: P1->(t+1).A-bot, P2->(t+1).B-bot,
// P3->(t+2).B-top [B-top last read P2], P4->(t+2).A-top [A-top last read P3];
// vmcnt(4) once per tile at P4, never 0 mid-loop). Clusters are output
// quadrants: (mm01,nn0) (mm01,nn1) (mm23,nn1) (mm23,nn0), 8 MFMA each —
// HALF the MFMA instruction count of the 16x16 version at +15% pipe rate.
// Frag layouts: A/B row=l&31, k=(l>>5)*8+e; C col=l&31,
// row=(reg&3)+8*(reg>>2)+4*(l>>5). LDS swizzle byte^=(row&7)<<4 both-sides.
__device__ __forceinline__ void core256w(const ushortT* __restrict__ A,
                                         const ushortT* __restrict__ Bm,
                                         ushortT* lds, int m0, int n0,
                                         float16v (&acc)[4][2]) {
  char* ldsb = (char*)lds;
  const int tid = threadIdx.x;
  const int w = tid >> 6, l = tid & 63;
  const int wm = w >> 2, wn = w & 3;          // 2 M-halves x 4 N-quarters

  // ---- staging addresses (linear LDS dest, pre-swizzled global source) ----
  const int P0b = tid * 16, P1b = 8192 + tid * 16;
  const int r0 = P0b >> 7, r1 = P1b >> 7;
  const int s0 = (P0b & 127) ^ ((r0 & 7) << 4);
  const int s1 = (P1b & 127) ^ ((r1 & 7) << 4);
  const size_t g0 = (size_t)r0 * 512 + (s0 >> 1);
  const size_t g1 = (size_t)r1 * 512 + (s1 >> 1);
  auto stage = [&](const ushortT* mat, int rowbase, int kt, int bufb, int region) {
    const ushortT* gsrc = mat + (size_t)rowbase * 512 + kt * 64;
    char* dbase = ldsb + bufb + region;
    gl_lds16(gsrc + g0, dbase + P0b);
    gl_lds16(gsrc + g1, dbase + P1b);
  };

  // ---- fragment read addressing ----
  const int rsw   = (l & 7) << 4;             // row-XOR swizzle term
  const int khalf = (l >> 5) * 16;            // k-group byte offset
  const int arow = wm * 16384 + (l & 31) * 128;
  const int brow = 32768 + wn * 8192 + (l & 31) * 128;

  short8v Af[2][4], Bf[2][4];
  auto rdA = [&](int bb, int mp) {            // 8 reads: mm = 2mp, 2mp+1
    #pragma unroll
    for (int m2 = 0; m2 < 2; ++m2)
      #pragma unroll
      for (int ks = 0; ks < 4; ++ks)
        Af[m2][ks] = *(const short8v*)(ldsb + bb + arow + (mp * 2 + m2) * 4096
                                       + ((ks * 32 + khalf) ^ rsw));
  };
  auto rdB = [&](int bb, int nn) {            // 4 reads
    #pragma unroll
    for (int ks = 0; ks < 4; ++ks)
      Bf[nn][ks] = *(const short8v*)(ldsb + bb + brow + nn * 4096
                                     + ((ks * 32 + khalf) ^ rsw));
  };
  auto cl = [&](int mp, int nn) {             // 8 MFMA (2 chains of 4)
    __builtin_amdgcn_s_setprio(1);
    #pragma unroll
    for (int m2 = 0; m2 < 2; ++m2)
      #pragma unroll
      for (int ks = 0; ks < 4; ++ks)
        MFMA32(acc[mp * 2 + m2][nn], Af[m2][ks], Bf[nn][ks]);
    __builtin_amdgcn_s_setprio(0);
  };

  auto tile = [&](int bb, int t1, int t2, bool s1g, bool s2g, int vw) {
    // P1: A mm0,1 (8) + B nn0 (4); stage (t+1).A-bot
    rdA(bb, 0); rdB(bb, 0);
    if (s1g) stage(A, m0 + 128, t1, bb ^ 65536, 16384);
    BAR(); LGKM0;
    cl(0, 0);
    BAR();
    // P2: B nn1 (4); stage (t+1).B-bot
    rdB(bb, 1);
    if (s1g) stage(Bm, n0 + 128, t1, bb ^ 65536, 49152);
    BAR(); LGKM0;
    cl(0, 1);
    BAR();
    // P3: A mm2,3 (8); stage (t+2).B-top (B-top last read in P2)
    rdA(bb, 1);
    if (s2g) stage(Bm, n0, t2, bb, 32768);
    BAR(); LGKM0;
    cl(1, 1);
    BAR();
    // P4: no reads; stage (t+2).A-top (A-top last read in P3); counted vmcnt
    if (s2g) stage(A, m0, t2, bb, 0);
    if (vw == 4)      { WAITV4; }
    else if (vw == 0) { WAITV0; }
    BAR();
    cl(1, 0);
    BAR();
  };

  // prologue: tile0 fully + tile1 B-top/A-top in flight
  stage(A,  m0,       0, 0, 0);
  stage(A,  m0 + 128, 0, 0, 16384);
  stage(Bm, n0,       0, 0, 32768);
  stage(Bm, n0 + 128, 0, 0, 49152);
  stage(Bm, n0,       1, 65536, 32768);
  stage(A,  m0,       1, 65536, 0);
  WAITV4;
  BAR();

  #pragma unroll 1
  for (int tp = 0; tp < 3; ++tp) {
    tile(0,     2 * tp + 1, 2 * tp + 2, true, true, 4);
    tile(65536, 2 * tp + 2, 2 * tp + 3, true, true, 4);
  }
  tile(0,     7, 8, true,  false, 0);
  tile(65536, 8, 9, false, false, -1);
}

// ---------------- K3: qkv GEMM (65536 x 1536 x 512) -> bf16 ----------------
// Persistent-n: one block per m-tile (grid 256 = 1 block/CU), loops 6 n-tiles.
__global__ __launch_bounds__(512, 2) void gemm_qkv(const ushortT* __restrict__ h,
                                                   const ushortT* __restrict__ wq,
                                                   const float* __restrict__ bias,
                                                   ushortT* __restrict__ outq) {
  __shared__ ushortT lds[65536];   // 128 KB
  const int m0 = blockIdx.x * 256;
  const int tid = threadIdx.x;
  const int w = tid >> 6, l = tid & 63;
  const int wm = w >> 2, wn = w & 3;
  const int lcol = l & 31, lhi = l >> 5;

  #pragma unroll 1
  for (int ni = 0; ni < 6; ++ni) {
    const int n0 = ni * 256;
    float16v acc[4][2] = {};
    core256w(h, wq, lds, m0, n0, acc);
    __syncthreads();
    // per-wave LDS transpose -> coalesced 64B/lane stores
    ushortT* es = lds + w * 2304;            // 32 x 72 shorts (144B pitch, 16B-aligned)
    float bb2[2];
    #pragma unroll
    for (int nn = 0; nn < 2; ++nn) bb2[nn] = bias[n0 + wn * 64 + nn * 32 + lcol];
    const int row2 = l >> 1, g = l & 1;
    #pragma unroll
    for (int mm = 0; mm < 4; ++mm) {
      #pragma unroll
      for (int nn = 0; nn < 2; ++nn)
        #pragma unroll
        for (int r = 0; r < 16; ++r) {
          int row = (r & 3) + 8 * (r >> 2) + 4 * lhi;
          es[row * 72 + nn * 32 + lcol] = f2bf(acc[mm][nn][r] + bb2[nn]);
        }
      const ushortT* ep = es + row2 * 72 + g * 32;
      uint4 v0 = *(const uint4*)(ep);
      uint4 v1 = *(const uint4*)(ep + 8);
      uint4 v2 = *(const uint4*)(ep + 16);
      uint4 v3 = *(const uint4*)(ep + 24);
      size_t mrow = (size_t)m0 + wm * 128 + mm * 32 + row2;
      uint4* dst = (uint4*)(outq + mrow * 1536 + n0 + wn * 64 + g * 32);
      dst[0] = v0; dst[1] = v1; dst[2] = v2; dst[3] = v3;
    }
    __syncthreads();
  }
}

// ---------------- K4: per-position 8x8 head attention (LDS-free) ----------
__global__ __launch_bounds__(256) void attn_k(const ushortT* __restrict__ qkv,
                                              ushortT* __restrict__ o) {
  int gp = blockIdx.x * 256 + threadIdx.x;
  int pos = gp >> 3, hh = gp & 7;
  const ushortT* base = qkv + (size_t)pos * 1536;
  float q[64];
  #pragma unroll
  for (int i = 0; i < 8; ++i) {
    uint4 u = *(const uint4*)(base + hh * 64 + i * 8);
    float2 t0 = up2(u.x), t1 = up2(u.y), t2 = up2(u.z), t3 = up2(u.w);
    q[i*8+0]=t0.x; q[i*8+1]=t0.y; q[i*8+2]=t1.x; q[i*8+3]=t1.y;
    q[i*8+4]=t2.x; q[i*8+5]=t2.y; q[i*8+6]=t3.x; q[i*8+7]=t3.y;
  }
  float lg[8];
  #pragma unroll
  for (int g = 0; g < 8; ++g) {
    float s = 0.f;
    #pragma unroll
    for (int d8 = 0; d8 < 8; ++d8) {
      uint4 kk = *(const uint4*)(base + 512 + g * 64 + d8 * 8);
      float2 k0 = up2(kk.x), k1 = up2(kk.y), k2 = up2(kk.z), k3 = up2(kk.w);
      s += q[d8*8+0]*k0.x + q[d8*8+1]*k0.y + q[d8*8+2]*k1.x + q[d8*8+3]*k1.y
         + q[d8*8+4]*k2.x + q[d8*8+5]*k2.y + q[d8*8+6]*k3.x + q[d8*8+7]*k3.y;
    }
    lg[g] = s * 0.125f;
  }
  float mx = lg[0];
  #pragma unroll
  for (int g = 1; g < 8; ++g) mx = fmaxf(mx, lg[g]);
  float ssum = 0.f;
  #pragma unroll
  for (int g = 0; g < 8; ++g) { lg[g] = __expf(lg[g] - mx); ssum += lg[g]; }
  float inv = 1.f / ssum;
  #pragma unroll
  for (int g = 0; g < 8; ++g) lg[g] *= inv;
  float oa[64];
  #pragma unroll
  for (int i = 0; i < 64; ++i) oa[i] = 0.f;
  #pragma unroll
  for (int g = 0; g < 8; ++g) {
    float wg = lg[g];
    #pragma unroll
    for (int d8 = 0; d8 < 8; ++d8) {
      uint4 vv = *(const uint4*)(base + 1024 + g * 64 + d8 * 8);
      float2 v0 = up2(vv.x), v1 = up2(vv.y), v2 = up2(vv.z), v3 = up2(vv.w);
      oa[d8*8+0] += wg*v0.x; oa[d8*8+1] += wg*v0.y;
      oa[d8*8+2] += wg*v1.x; oa[d8*8+3] += wg*v1.y;
      oa[d8*8+4] += wg*v2.x; oa[d8*8+5] += wg*v2.y;
      oa[d8*8+6] += wg*v3.x; oa[d8*8+7] += wg*v3.y;
    }
  }
  ushortT* dst = o + (size_t)pos * 512 + hh * 64;
  #pragma unroll
  for (int i = 0; i < 8; ++i) {
    uint4 w_;
    w_.x = (unsigned)f2bf(oa[i*8+0]) | ((unsigned)f2bf(oa[i*8+1]) << 16);
    w_.y = (unsigned)f2bf(oa[i*8+2]) | ((unsigned)f2bf(oa[i*8+3]) << 16);
    w_.z = (unsigned)f2bf(oa[i*8+4]) | ((unsigned)f2bf(oa[i*8+5]) << 16);
    w_.w = (unsigned)f2bf(oa[i*8+6]) | ((unsigned)f2bf(oa[i*8+7]) << 16);
    *(uint4*)(dst + i * 8) = w_;
  }
}

// ---------------- K5: proj GEMM + residual + transposed fp32 write ---------
// Persistent-n: one block per m-tile (grid 256), loops 2 n-tiles.
__global__ __launch_bounds__(512, 2) void gemm_proj(const ushortT* __restrict__ o,
                                                    const ushortT* __restrict__ wp,
                                                    const float* __restrict__ bias,
                                                    const float* __restrict__ x,
                                                    float* __restrict__ out) {
  __shared__ ushortT lds[65536];
  const int m0 = blockIdx.x * 256;
  const int tid = threadIdx.x;
  const int w = tid >> 6, l = tid & 63;
  const int wm = w >> 2, wn = w & 3;
  const int lcol = l & 31, lhi = l >> 5;
  const int b = m0 >> 12;                      // m-tile never straddles a batch
  const int nb0 = (m0 & 4095) + wm * 128;

  #pragma unroll 1
  for (int ni = 0; ni < 2; ++ni) {
    const int n0 = ni * 256;
    float16v acc[4][2] = {};
    core256w(o, wp, lds, m0, n0, acc);
    __syncthreads();
    float* esf = (float*)((char*)lds + w * 9216);   // 64 x 36 floats (16B-aligned pitch)
    const int c = n0 + wn * 64 + l;                 // one channel per lane
    const float bc = bias[c];
    const float* xrow = x + ((size_t)b * 512 + c) * 4096;
    float* orow = out + ((size_t)b * 512 + c) * 4096;
    #pragma unroll
    for (int mm = 0; mm < 4; ++mm) {
      #pragma unroll
      for (int nn = 0; nn < 2; ++nn)
        #pragma unroll
        for (int r = 0; r < 16; ++r) {
          int pos = (r & 3) + 8 * (r >> 2) + 4 * lhi;
          esf[(nn * 32 + lcol) * 36 + pos] = acc[mm][nn][r];
        }
      int nb = nb0 + mm * 32;
      #pragma unroll
      for (int pg = 0; pg < 8; ++pg) {
        float4 xv = *(const float4*)(xrow + nb + pg * 4);
        float4 ev = *(const float4*)(esf + l * 36 + pg * 4);
        float4 ov;
        ov.x = xv.x + bc + ev.x;
        ov.y = xv.y + bc + ev.y;
        ov.z = xv.z + bc + ev.z;
        ov.w = xv.w + bc + ev.w;
        *(float4*)(orow + nb + pg * 4) = ov;
      }
      __syncthreads();   // esf region reused by same wave next mm; cheap full sync
    }
    __syncthreads();
  }
}

// ---------------- launcher ----------------
extern "C" void kernel_launch(void* const* d_in, const int* in_sizes, int n_in,
                              void* d_out, int out_size, void* d_ws, size_t ws_size,
                              hipStream_t stream) {
  const float* x     = (const float*)d_in[0];
  const float* nw    = (const float*)d_in[1];
  const float* nb    = (const float*)d_in[2];
  const float* qkvw  = (const float*)d_in[3];
  const float* qkvb  = (const float*)d_in[4];
  const float* pw    = (const float*)d_in[5];
  const float* pb    = (const float*)d_in[6];
  float* out = (float*)d_out;
  char* ws = (char*)d_ws;

  const size_t OFF_WQ   = 4096;
  const size_t OFF_WP   = OFF_WQ + 1572864;
  const size_t OFF_H    = OFF_WP + 524288;
  const size_t OFF_QKV  = OFF_H + 67108864;

  float2* stats   = (float2*)ws;
  ushortT* wq_b   = (ushortT*)(ws + OFF_WQ);
  ushortT* wp_b   = (ushortT*)(ws + OFF_WP);
  ushortT* h      = (ushortT*)(ws + OFF_H);
  ushortT* qkv    = (ushortT*)(ws + OFF_QKV);

  wconv<<<768, 256, 0, stream>>>(qkvw, wq_b, 786432);
  wconv<<<256, 256, 0, stream>>>(pw,   wp_b, 262144);
  gn_stats<<<512, 256, 0, stream>>>(x, stats);
  norm_tr<<<dim3(64, 8, 16), dim3(64, 8), 0, stream>>>(x, nw, nb, stats, h);
  gemm_qkv<<<256, 512, 0, stream>>>(h, wq_b, qkvb, qkv);
  attn_k<<<2048, 256, 0, stream>>>(qkv, h);
  gemm_proj<<<256, 512, 0, stream>>>(h, wp_b, pb, x, out);
}

// Round 6
// 397.714 us; speedup vs baseline: 1.1629x; 1.1629x over previous
//
#include <hip/hip_runtime.h>

// ---------------- types / helpers ----------------
typedef __attribute__((ext_vector_type(8))) short short8v;   // 8 bf16 (4 VGPR)
typedef __attribute__((ext_vector_type(4))) float float4v;   // MFMA acc
typedef unsigned short ushortT;

__device__ __forceinline__ unsigned short f2bf(float f) {
  union { float f; unsigned u; } a; a.f = f;
  unsigned r = a.u + 0x7fffu + ((a.u >> 16) & 1u);   // RNE
  return (unsigned short)(r >> 16);
}
__device__ __forceinline__ float2 up2(unsigned u) {  // packed 2xbf16 -> 2 floats
  union { unsigned u; float f; } a, b;
  a.u = u << 16; b.u = u & 0xffff0000u;
  return make_float2(a.f, b.f);
}
__device__ __forceinline__ void gl_lds16(const void* g, void* l) {
  __builtin_amdgcn_global_load_lds(
      (const __attribute__((address_space(1))) void*)g,
      (__attribute__((address_space(3))) void*)l, 16, 0, 0);
}

#define WAITV4 asm volatile("s_waitcnt vmcnt(4)" ::: "memory")
#define WAITV0 asm volatile("s_waitcnt vmcnt(0)" ::: "memory")
#define BAR()  __builtin_amdgcn_s_barrier()
#define MFMA16(d, a, b) d = __builtin_amdgcn_mfma_f32_16x16x32_bf16(a, b, d, 0, 0, 0)

// ---------------- K0: fused prep — weight converts + groupnorm stats -------
// blocks [0,768): qkv_w -> bf16 ; [768,1024): proj_w -> bf16 ;
// blocks [1024,1536): per-(b,g) mean/rsqrt-var over 16ch x 4096.
__global__ __launch_bounds__(256) void prep(const float* __restrict__ qkvw,
                                            const float* __restrict__ pw,
                                            const float* __restrict__ x,
                                            ushortT* __restrict__ wq_b,
                                            ushortT* __restrict__ wp_b,
                                            float2* __restrict__ stats) {
  int bid = blockIdx.x, tid = threadIdx.x;
  if (bid < 1024) {
    const float* src = (bid < 768) ? qkvw : pw;
    ushortT* dst     = (bid < 768) ? wq_b : wp_b;
    int base = (bid < 768) ? bid : (bid - 768);
    int i = (base * 256 + tid) * 4;
    float4 v = *(const float4*)(src + i);
    uint2 o;
    o.x = (unsigned)f2bf(v.x) | ((unsigned)f2bf(v.y) << 16);
    o.y = (unsigned)f2bf(v.z) | ((unsigned)f2bf(v.w) << 16);
    *(uint2*)(dst + i) = o;
    return;
  }
  int bg = bid - 1024;
  const float* base = x + (size_t)bg * 65536;
  float s = 0.f, s2 = 0.f;
  for (int i = tid; i < 16384; i += 256) {
    float4 v = *(const float4*)(base + (size_t)i * 4);
    s  += v.x + v.y + v.z + v.w;
    s2 += v.x * v.x + v.y * v.y + v.z * v.z + v.w * v.w;
  }
  #pragma unroll
  for (int off = 32; off > 0; off >>= 1) {
    s  += __shfl_down(s, off);
    s2 += __shfl_down(s2, off);
  }
  __shared__ float red[8];
  int w = tid >> 6, l = tid & 63;
  if (l == 0) { red[w] = s; red[w + 4] = s2; }
  __syncthreads();
  if (tid == 0) {
    float ts = red[0] + red[1] + red[2] + red[3];
    float t2 = red[4] + red[5] + red[6] + red[7];
    float mean = ts * (1.f / 65536.f);
    float var  = t2 * (1.f / 65536.f) - mean * mean;
    stats[bg] = make_float2(mean, rsqrtf(var + 1e-5f));
  }
}

// ---------------- K2: normalize + transpose -> h[b*n][c] bf16 ----------------
__global__ __launch_bounds__(512) void norm_tr(const float* __restrict__ x,
                                               const float* __restrict__ nw,
                                               const float* __restrict__ nb,
                                               const float2* __restrict__ stats,
                                               ushortT* __restrict__ h) {
  __shared__ float t[64][65];
  int n0 = blockIdx.x * 64, c0 = blockIdx.y * 64, b = blockIdx.z;
  int tx = threadIdx.x, ty = threadIdx.y;
  #pragma unroll
  for (int j = ty; j < 64; j += 8) {
    int c = c0 + j;
    float2 ms = stats[b * 32 + (c >> 4)];
    float v = x[((size_t)b * 512 + c) * 4096 + n0 + tx];
    t[j][tx] = (v - ms.x) * ms.y * nw[c] + nb[c];
  }
  __syncthreads();
  #pragma unroll
  for (int j = ty; j < 64; j += 8) {
    int n = n0 + j;
    h[((size_t)b * 4096 + n) * 512 + c0 + tx] = f2bf(t[tx][j]);
  }
}

// ================= 256x256 8-wave 8-phase GEMM core ========================
// K=512, BK=64, 2 LDS buffers of 64KB. Region map (race-free):
// P1->(t+1).A-bot, P2->(t+1).B-bot, P3->(t+2).B-top [last read P2],
// P4->(t+2).A-top [last read P3]; vmcnt(4) once per tile at P4 (never 0
// mid-loop). NO explicit lgkmcnt: fragment reads are plain C++ ds_reads, the
// compiler inserts per-operand fine-grained lgkmcnt before each MFMA — a
// blanket lgkmcnt(0) would serialize the full 12-read drain before the first
// MFMA of every cluster. B-frags read before A so first MFMA's operands land
// earliest. LDS swizzle byte^=(row&7)<<4 both-sides (pre-swizzled global src).
__device__ __forceinline__ void core256b(const ushortT* __restrict__ A,
                                         const ushortT* __restrict__ Bm,
                                         ushortT* lds, int m0, int n0,
                                         float4v (&acc)[8][4]) {
  char* ldsb = (char*)lds;
  const int tid = threadIdx.x;
  const int w = tid >> 6, l = tid & 63;
  const int wm = w >> 2, wn = w & 3;

  const int P0b = tid * 16, P1b = 8192 + tid * 16;
  const int r0 = P0b >> 7, r1 = P1b >> 7;
  const int s0 = (P0b & 127) ^ ((r0 & 7) << 4);
  const int s1 = (P1b & 127) ^ ((r1 & 7) << 4);
  const size_t g0 = (size_t)r0 * 512 + (s0 >> 1);
  const size_t g1 = (size_t)r1 * 512 + (s1 >> 1);
  auto stage = [&](const ushortT* mat, int rowbase, int kt, int bufb, int region) {
    const ushortT* gsrc = mat + (size_t)rowbase * 512 + kt * 64;
    char* dbase = ldsb + bufb + region;
    gl_lds16(gsrc + g0, dbase + P0b);
    gl_lds16(gsrc + g1, dbase + P1b);
  };

  const int colb = (l >> 4) * 16;
  const int cs0 = colb ^ ((l & 7) << 4);
  const int cs1 = (64 + colb) ^ ((l & 7) << 4);
  const int arow = wm * 16384 + (l & 15) * 128;
  const int brow = 32768 + wn * 8192 + (l & 15) * 128;

  short8v Af[4][2], Bf[4][2];

  #define RDA4(bb, MH)                                                  \
    { _Pragma("unroll")                                                 \
      for (int mm = 0; mm < 4; ++mm) {                                  \
        const char* p = ldsb + (bb) + arow + ((MH)*4 + mm) * 2048;      \
        Af[mm][0] = *(const short8v*)(p + cs0);                         \
        Af[mm][1] = *(const short8v*)(p + cs1);                         \
      } }
  #define RDB2(bb, N0)                                                  \
    { _Pragma("unroll")                                                 \
      for (int nn = 0; nn < 2; ++nn) {                                  \
        const char* p = ldsb + (bb) + brow + ((N0) + nn) * 2048;        \
        Bf[(N0)+nn][0] = *(const short8v*)(p + cs0);                    \
        Bf[(N0)+nn][1] = *(const short8v*)(p + cs1);                    \
      } }
  #define CLUSTER(MH, NP)                                               \
    { __builtin_amdgcn_s_setprio(1);                                    \
      _Pragma("unroll")                                                 \
      for (int mm = 0; mm < 4; ++mm) {                                  \
        _Pragma("unroll")                                               \
        for (int nn = 0; nn < 2; ++nn) {                                \
          MFMA16(acc[(MH)*4+mm][(NP)*2+nn], Af[mm][0], Bf[(NP)*2+nn][0]); \
          MFMA16(acc[(MH)*4+mm][(NP)*2+nn], Af[mm][1], Bf[(NP)*2+nn][1]); \
        } }                                                             \
      __builtin_amdgcn_s_setprio(0); }

  auto tile = [&](int bb, int t1, int t2, bool s1g, bool s2g, int vw) {
    // P1: B n0-1 first, then A m0-3 (12 reads); stage (t+1).A-bot
    RDB2(bb, 0); RDA4(bb, 0);
    if (s1g) stage(A, m0 + 128, t1, bb ^ 65536, 16384);
    BAR();
    CLUSTER(0, 0);
    BAR();
    // P2: B n2-3 (4); stage (t+1).B-bot
    RDB2(bb, 2);
    if (s1g) stage(Bm, n0 + 128, t1, bb ^ 65536, 49152);
    BAR();
    CLUSTER(0, 1);
    BAR();
    // P3: A m4-7 (8); stage (t+2).B-top
    RDA4(bb, 1);
    if (s2g) stage(Bm, n0, t2, bb, 32768);
    BAR();
    CLUSTER(1, 1);
    BAR();
    // P4: no reads; stage (t+2).A-top; per-tile counted vmcnt
    if (s2g) stage(A, m0, t2, bb, 0);
    if (vw == 4)      { WAITV4; }
    else if (vw == 0) { WAITV0; }
    BAR();
    CLUSTER(1, 0);
    BAR();
  };

  // prologue
  stage(A,  m0,       0, 0, 0);
  stage(A,  m0 + 128, 0, 0, 16384);
  stage(Bm, n0,       0, 0, 32768);
  stage(Bm, n0 + 128, 0, 0, 49152);
  stage(Bm, n0,       1, 65536, 32768);
  stage(A,  m0,       1, 65536, 0);
  WAITV4;
  BAR();

  #pragma unroll 1
  for (int tp = 0; tp < 3; ++tp) {
    tile(0,     2 * tp + 1, 2 * tp + 2, true, true, 4);
    tile(65536, 2 * tp + 2, 2 * tp + 3, true, true, 4);
  }
  tile(0,     7, 8, true,  false, 0);
  tile(65536, 8, 9, false, false, -1);
  #undef RDA4
  #undef RDB2
  #undef CLUSTER
}

// ---------------- K3: qkv GEMM (65536 x 1536 x 512) -> bf16 ----------------
__global__ __launch_bounds__(512, 2) void gemm_qkv(const ushortT* __restrict__ h,
                                                   const ushortT* __restrict__ wq,
                                                   const float* __restrict__ bias,
                                                   ushortT* __restrict__ outq) {
  __shared__ ushortT lds[65536];   // 128 KB
  int bid = blockIdx.x;
  int wg = (bid & 7) * 192 + (bid >> 3);         // bijective XCD swizzle
  int m0 = (wg / 6) * 256, n0 = (wg % 6) * 256;  // N fastest -> A reused in L2
  float4v acc[8][4] = {};
  core256b(h, wq, lds, m0, n0, acc);
  const int tid = threadIdx.x;
  const int w = tid >> 6, l = tid & 63;
  const int wm = w >> 2, wn = w & 3;
  __syncthreads();
  ushortT* es = lds + w * 1280;              // 16 x 72 shorts per wave
  float bb[4];
  #pragma unroll
  for (int fn = 0; fn < 4; ++fn) bb[fn] = bias[n0 + wn * 64 + fn * 16 + (l & 15)];
  int r = l >> 2, g = l & 3;
  #pragma unroll
  for (int fm = 0; fm < 8; ++fm) {
    #pragma unroll
    for (int fn = 0; fn < 4; ++fn)
      #pragma unroll
      for (int j = 0; j < 4; ++j)
        es[((l >> 4) * 4 + j) * 72 + fn * 16 + (l & 15)] = f2bf(acc[fm][fn][j] + bb[fn]);
    uint4 v0 = *(const uint4*)(es + r * 72 + g * 16);
    uint4 v1 = *(const uint4*)(es + r * 72 + g * 16 + 8);
    size_t mrow = (size_t)m0 + wm * 128 + fm * 16 + r;
    uint4* dst = (uint4*)(outq + mrow * 1536 + n0 + wn * 64 + g * 16);
    dst[0] = v0; dst[1] = v1;
  }
}

// ---------------- K4: per-position 8x8 head attention (LDS-free) ----------
__global__ __launch_bounds__(256) void attn_k(const ushortT* __restrict__ qkv,
                                              ushortT* __restrict__ o) {
  int gp = blockIdx.x * 256 + threadIdx.x;
  int pos = gp >> 3, hh = gp & 7;
  const ushortT* base = qkv + (size_t)pos * 1536;
  float q[64];
  #pragma unroll
  for (int i = 0; i < 8; ++i) {
    uint4 u = *(const uint4*)(base + hh * 64 + i * 8);
    float2 t0 = up2(u.x), t1 = up2(u.y), t2 = up2(u.z), t3 = up2(u.w);
    q[i*8+0]=t0.x; q[i*8+1]=t0.y; q[i*8+2]=t1.x; q[i*8+3]=t1.y;
    q[i*8+4]=t2.x; q[i*8+5]=t2.y; q[i*8+6]=t3.x; q[i*8+7]=t3.y;
  }
  float lg[8];
  #pragma unroll
  for (int g = 0; g < 8; ++g) {
    float s = 0.f;
    #pragma unroll
    for (int d8 = 0; d8 < 8; ++d8) {
      uint4 kk = *(const uint4*)(base + 512 + g * 64 + d8 * 8);
      float2 k0 = up2(kk.x), k1 = up2(kk.y), k2 = up2(kk.z), k3 = up2(kk.w);
      s += q[d8*8+0]*k0.x + q[d8*8+1]*k0.y + q[d8*8+2]*k1.x + q[d8*8+3]*k1.y
         + q[d8*8+4]*k2.x + q[d8*8+5]*k2.y + q[d8*8+6]*k3.x + q[d8*8+7]*k3.y;
    }
    lg[g] = s * 0.125f;
  }
  float mx = lg[0];
  #pragma unroll
  for (int g = 1; g < 8; ++g) mx = fmaxf(mx, lg[g]);
  float ssum = 0.f;
  #pragma unroll
  for (int g = 0; g < 8; ++g) { lg[g] = __expf(lg[g] - mx); ssum += lg[g]; }
  float inv = 1.f / ssum;
  #pragma unroll
  for (int g = 0; g < 8; ++g) lg[g] *= inv;
  float oa[64];
  #pragma unroll
  for (int i = 0; i < 64; ++i) oa[i] = 0.f;
  #pragma unroll
  for (int g = 0; g < 8; ++g) {
    float wg = lg[g];
    #pragma unroll
    for (int d8 = 0; d8 < 8; ++d8) {
      uint4 vv = *(const uint4*)(base + 1024 + g * 64 + d8 * 8);
      float2 v0 = up2(vv.x), v1 = up2(vv.y), v2 = up2(vv.z), v3 = up2(vv.w);
      oa[d8*8+0] += wg*v0.x; oa[d8*8+1] += wg*v0.y;
      oa[d8*8+2] += wg*v1.x; oa[d8*8+3] += wg*v1.y;
      oa[d8*8+4] += wg*v2.x; oa[d8*8+5] += wg*v2.y;
      oa[d8*8+6] += wg*v3.x; oa[d8*8+7] += wg*v3.y;
    }
  }
  ushortT* dst = o + (size_t)pos * 512 + hh * 64;
  #pragma unroll
  for (int i = 0; i < 8; ++i) {
    uint4 w_;
    w_.x = (unsigned)f2bf(oa[i*8+0]) | ((unsigned)f2bf(oa[i*8+1]) << 16);
    w_.y = (unsigned)f2bf(oa[i*8+2]) | ((unsigned)f2bf(oa[i*8+3]) << 16);
    w_.z = (unsigned)f2bf(oa[i*8+4]) | ((unsigned)f2bf(oa[i*8+5]) << 16);
    w_.w = (unsigned)f2bf(oa[i*8+6]) | ((unsigned)f2bf(oa[i*8+7]) << 16);
    *(uint4*)(dst + i * 8) = w_;
  }
}

// ---------------- K5: proj GEMM + residual + transposed fp32 write ---------
__global__ __launch_bounds__(512, 2) void gemm_proj(const ushortT* __restrict__ o,
                                                    const ushortT* __restrict__ wp,
                                                    const float* __restrict__ bias,
                                                    const float* __restrict__ x,
                                                    float* __restrict__ out) {
  __shared__ ushortT lds[65536];
  int bid = blockIdx.x;
  int wg = (bid & 7) * 64 + (bid >> 3);      // bijective XCD swizzle
  int m0 = (wg >> 1) * 256, n0 = (wg & 1) * 256;
  float4v acc[8][4] = {};
  core256b(o, wp, lds, m0, n0, acc);
  const int tid = threadIdx.x;
  const int w = tid >> 6, l = tid & 63;
  const int wm = w >> 2, wn = w & 3;
  __syncthreads();
  float* es = (float*)((char*)lds + w * 4608);   // 16 x 68 floats, wave-disjoint
  int b = m0 >> 12;
  int c = n0 + wn * 64 + l;
  float bc = bias[c];
  const float* xrow = x + ((size_t)b * 512 + c) * 4096;
  float* orow = out + ((size_t)b * 512 + c) * 4096;
  int nb0 = (m0 & 4095) + wm * 128;
  #pragma unroll
  for (int fm = 0; fm < 8; ++fm) {
    #pragma unroll
    for (int fn = 0; fn < 4; ++fn)
      #pragma unroll
      for (int j = 0; j < 4; ++j)
        es[((l >> 4) * 4 + j) * 68 + fn * 16 + (l & 15)] = acc[fm][fn][j];
    // same-wave LDS write->read: compiler inserts lgkmcnt; no barrier needed
    int nb = nb0 + fm * 16;
    #pragma unroll
    for (int q4 = 0; q4 < 4; ++q4) {
      float4 xv = *(const float4*)(xrow + nb + q4 * 4);
      float4 ov;
      ov.x = xv.x + bc + es[(q4 * 4 + 0) * 68 + l];
      ov.y = xv.y + bc + es[(q4 * 4 + 1) * 68 + l];
      ov.z = xv.z + bc + es[(q4 * 4 + 2) * 68 + l];
      ov.w = xv.w + bc + es[(q4 * 4 + 3) * 68 + l];
      *(float4*)(orow + nb + q4 * 4) = ov;
    }
  }
}

// ---------------- launcher ----------------
extern "C" void kernel_launch(void* const* d_in, const int* in_sizes, int n_in,
                              void* d_out, int out_size, void* d_ws, size_t ws_size,
                              hipStream_t stream) {
  const float* x     = (const float*)d_in[0];
  const float* nw    = (const float*)d_in[1];
  const float* nb    = (const float*)d_in[2];
  const float* qkvw  = (const float*)d_in[3];
  const float* qkvb  = (const float*)d_in[4];
  const float* pw    = (const float*)d_in[5];
  const float* pb    = (const float*)d_in[6];
  float* out = (float*)d_out;
  char* ws = (char*)d_ws;

  const size_t OFF_WQ   = 4096;
  const size_t OFF_WP   = OFF_WQ + 1572864;
  const size_t OFF_H    = OFF_WP + 524288;
  const size_t OFF_QKV  = OFF_H + 67108864;

  float2* stats   = (float2*)ws;
  ushortT* wq_b   = (ushortT*)(ws + OFF_WQ);
  ushortT* wp_b   = (ushortT*)(ws + OFF_WP);
  ushortT* h      = (ushortT*)(ws + OFF_H);
  ushortT* qkv    = (ushortT*)(ws + OFF_QKV);

  prep<<<1536, 256, 0, stream>>>(qkvw, pw, x, wq_b, wp_b, stats);
  norm_tr<<<dim3(64, 8, 16), dim3(64, 8), 0, stream>>>(x, nw, nb, stats, h);
  gemm_qkv<<<1536, 512, 0, stream>>>(h, wq_b, qkvb, qkv);
  attn_k<<<2048, 256, 0, stream>>>(qkv, h);
  gemm_proj<<<512, 512, 0, stream>>>(h, wp_b, pb, x, out);
}